// Round 9
// baseline (255.783 us; speedup 1.0000x reference)
//
#include <hip/hip_runtime.h>

#define N_NODES 100000
#define N_EDGES 1600000
#define CAP 48      // deg~Poisson(16); P(deg>=48)*N ~ 3e-6 -> no drops
#define NBUCK 256   // dst-range buckets
#define NPB 391     // nodes per bucket = ceil(100000/256)
#define EPB 4096    // edges per bin block slab
#define NBIN ((N_EDGES + EPB - 1) / EPB)     // 391
#define OFSW 257    // per-slab offset-table width (256 starts + total)

typedef unsigned int uint;
typedef unsigned short ushort;

__device__ __forceinline__ void fma4(float4& c, float s, const float4& w) {
    c.x += s * w.x; c.y += s * w.y; c.z += s * w.z; c.w += s * w.w;
}

__device__ __forceinline__ ushort bf16r(float f) {   // fp32 -> bf16 RNE
    union { float f; uint u; } v; v.f = f;
    return (ushort)((v.u + 0x7fffu + ((v.u >> 16) & 1u)) >> 16);
}

// ---------------- fp32 GEMM block: 128 rows x 64 cols, 8x4 thread tile --------
// r5: 8-consecutive-rows/thread tiles are structurally bank-conflicted; r7/r8:
// row-interleave (rows rg+16*r) kept; r8 showed the residual 126K conflicts
// come from the CSR lc atomics, NOT this GEMM — tile is closed.
struct alignas(16) GemmSmem {
    float Xs[128][36];   // stride 36: 16B-aligned rows
    float Ws[32][64];
};

template <typename OutT>
__device__ __forceinline__ void gemm64_block(GemmSmem& sm, int bid,
                                             const float* __restrict__ X,
                                             const float* __restrict__ W,
                                             OutT* __restrict__ H, int n) {
    const int tid  = threadIdx.x;
    const int row0 = bid * 128;
    const int rg   = tid >> 4;          // 0..15: rows rg, rg+16, ..., rg+112
    const int cg   = tid & 15;          // col group: cg*4

    float4 acc0[8];
#pragma unroll
    for (int r = 0; r < 8; r++) acc0[r] = make_float4(0.f, 0.f, 0.f, 0.f);

    const int lr = tid >> 1;
    const int lh = tid & 1;
    int grow = row0 + lr; if (grow > n - 1) grow = n - 1;   // clamp tail reads
    const float* gx_base = X + (size_t)grow * 128 + lh * 16;

    for (int k0 = 0; k0 < 128; k0 += 32) {
        const float* gx = gx_base + k0;
#pragma unroll
        for (int i = 0; i < 4; i++)
            *(float4*)&sm.Xs[lr][lh * 16 + 4 * i] = *(const float4*)(gx + 4 * i);
        const float4* gw = (const float4*)(W + (size_t)k0 * 64);
        float4* sw = (float4*)&sm.Ws[0][0];
#pragma unroll
        for (int i = 0; i < 2; i++) sw[tid + 256 * i] = gw[tid + 256 * i];
        __syncthreads();

#pragma unroll
        for (int kk = 0; kk < 32; kk += 4) {
            float4 w00 = *(const float4*)&sm.Ws[kk + 0][cg * 4];
            float4 w01 = *(const float4*)&sm.Ws[kk + 1][cg * 4];
            float4 w02 = *(const float4*)&sm.Ws[kk + 2][cg * 4];
            float4 w03 = *(const float4*)&sm.Ws[kk + 3][cg * 4];
#pragma unroll
            for (int r = 0; r < 8; r++) {
                float4 a = *(const float4*)&sm.Xs[rg + 16 * r][kk];
                fma4(acc0[r], a.x, w00);
                fma4(acc0[r], a.y, w01);
                fma4(acc0[r], a.z, w02);
                fma4(acc0[r], a.w, w03);
            }
        }
        __syncthreads();
    }

#pragma unroll
    for (int r = 0; r < 8; r++) {
        int row = row0 + rg + 16 * r;
        if (row < n) {
            if constexpr (sizeof(OutT) == 2) {   // bf16 epilogue, node-major
                ushort4 o0 = make_ushort4(bf16r(acc0[r].x), bf16r(acc0[r].y),
                                          bf16r(acc0[r].z), bf16r(acc0[r].w));
                *(ushort4*)&H[(size_t)row * 64 + cg * 4] = o0;
            } else {
                *(float4*)&H[(size_t)row * 64 + cg * 4] = *(float4*)&acc0[r];
            }
        }
    }
}

// ---------------- Pass A + weight collapse (fused) ----------------
// Round-9 restructure: NO cross-block reservation protocol. Each bin block
// bucket-sorts its 4096 edges in LDS (hist slot + scan) and writes them to
// its OWN contiguous 32 KB slab (stage[blk]) + a 257-entry offset table.
// Zero global atomics, fully coalesced writes, no capacity hazard, no memset.
// (r4-r8: gcur-protocol variants all pinned bin at ~40 us, VALU 3%, HBM 6%;
// this round is the falsification test for "the protocol is the stall".)
union BinWcSmem {
    struct {
        int ecnt[NBUCK];
        int lofs[NBUCK];
        uint2 estage[EPB];   // 32 KB bucket-sorted staging
    } b;                     // 34 KB
    GemmSmem g;              // 26.6 KB
};

__global__ void __launch_bounds__(256) bin_wc(const int* __restrict__ src,
                                              const int* __restrict__ dst,
                                              uint2* __restrict__ stage,
                                              int* __restrict__ ofs, int E,
                                              const float* __restrict__ W1,
                                              const float* __restrict__ W2,
                                              const float* __restrict__ W3,
                                              float* __restrict__ W23,
                                              float* __restrict__ Wc) {
    __shared__ BinWcSmem sh;
    if (blockIdx.x == NBIN) {               // weight-collapse block
        gemm64_block<float>(sh.g, 0, W2, W3, W23, 128);
        __syncthreads();                     // W23 global writes visible in-block
        gemm64_block<float>(sh.g, 0, W1, W23, Wc, 128);
        return;
    }
    const int t = threadIdx.x;
    sh.b.ecnt[t] = 0;                        // t spans exactly NBUCK
    __syncthreads();
    const int e0 = blockIdx.x * EPB;
    const int total = min(E - e0, EPB);
    uint sreg[EPB / 256];
    int  dreg[EPB / 256];
    int  slreg[EPB / 256];
    // phase 1: LDS histogram; returned value IS this edge's in-bucket slot
#pragma unroll
    for (int k = 0; k < EPB / 256; k++) {
        int i = e0 + k * 256 + t;
        if (i < E) {
            int d = dst[i];
            sreg[k] = (uint)src[i];
            dreg[k] = d;
            slreg[k] = atomicAdd(&sh.b.ecnt[d / NPB], 1);
        }
    }
    __syncthreads();
    // phase 2: exclusive scan of ecnt -> lofs (Hillis-Steele over 256)
    const int c = sh.b.ecnt[t];
    sh.b.lofs[t] = c;
    __syncthreads();
#pragma unroll
    for (int off = 1; off < NBUCK; off <<= 1) {
        int u = (t >= off) ? sh.b.lofs[t - off] : 0;
        __syncthreads();
        sh.b.lofs[t] += u;
        __syncthreads();
    }
    const int excl = sh.b.lofs[t] - c;       // inclusive -> exclusive
    __syncthreads();
    sh.b.lofs[t] = excl;
    // publish this slab's offset table
    ofs[blockIdx.x * OFSW + t] = excl;
    if (t == NBUCK - 1) ofs[blockIdx.x * OFSW + NBUCK] = excl + c;  // = total
    __syncthreads();
    // phase 3a: stage edges bucket-sorted in LDS
#pragma unroll
    for (int k = 0; k < EPB / 256; k++) {
        int i = e0 + k * 256 + t;
        if (i < E) {
            int b = dreg[k] / NPB;
            sh.b.estage[sh.b.lofs[b] + slreg[k]] =
                make_uint2(sreg[k], (uint)dreg[k]);
        }
    }
    __syncthreads();
    // phase 3b: contiguous coalesced slab writeout (16 B lanes; total is even)
    uint4* out = (uint4*)(stage + (size_t)blockIdx.x * EPB);
    const uint4* in = (const uint4*)sh.b.estage;
    for (int i = t; i < total / 2; i += 256) out[i] = in[i];
}

// ---------------- Pass B + main GEMM (fused, heterogeneous blocks) ----------------
// CSR build: bucket b walks the 391 slabs; thread g reads run
// [ofs[g][b], ofs[g][b+1]) — avg 16 edges = 128 B contiguous, L2/MALL-
// resident. Overlapped with Y = X @ Wc (pipe-disjoint pairing, r1-proven).
union CsrGemmSmem {
    int lc[NPB];
    GemmSmem g;
};

__global__ void __launch_bounds__(256, 3) csr_gemm(const int* __restrict__ ofs,
                                                   const uint2* __restrict__ stage,
                                                   int* __restrict__ col,
                                                   int* __restrict__ cnt,
                                                   const float* __restrict__ X,
                                                   const float* __restrict__ Wc,
                                                   ushort* __restrict__ Y, int n) {
    __shared__ CsrGemmSmem sh;
    if (blockIdx.x < NBUCK) {
        const int b = blockIdx.x;
        const int t = threadIdx.x;
        for (int i = t; i < NPB; i += 256) sh.lc[i] = 0;
        __syncthreads();
        const int node0 = b * NPB;
        for (int g = t; g < NBIN; g += 256) {
            int o0 = ofs[g * OFSW + b];
            int o1 = ofs[g * OFSW + b + 1];
            const uint2* sg = stage + (size_t)g * EPB;
            for (int i = o0; i < o1; i++) {
                uint2 e = sg[i];
                int d = (int)e.y;
                int slot = atomicAdd(&sh.lc[d - node0], 1);
                if (slot < CAP) col[(size_t)d * CAP + slot] = (int)e.x;
            }
        }
        __syncthreads();
        for (int i = t; i < NPB; i += 256) {
            int node = node0 + i;
            if (node < n) cnt[node] = (sh.lc[i] > CAP) ? CAP : sh.lc[i];
        }
    } else {
        gemm64_block<ushort>(sh.g, blockIdx.x - NBUCK, X, Wc, Y, n);
    }
}

// ---------------- Aggregation, width 64, bf16 table [N][64] ----------------
// 8 lanes per node; lane owns a uint4 (8 dims) -> one coalesced 128 B
// (exactly one cacheline) gather per edge. r2: no dim-split. r0/r4: at the
// random-gather MALL service floor (~5.5 TB/s effective); lane-shape neutral.
__device__ __forceinline__ float2 bf2f(uint u) {
    union { uint u; float f; } a, b;
    a.u = u << 16; b.u = u & 0xffff0000u;
    return make_float2(a.f, b.f);
}

template <bool FINAL>
__global__ void __launch_bounds__(256) agg64(const uint4* __restrict__ T_in,
                                             const int* __restrict__ cnt,
                                             const int* __restrict__ col,
                                             void* __restrict__ T_out, int n) {
    int gid  = blockIdx.x * blockDim.x + threadIdx.x;
    int node = gid >> 3;
    int lane = gid & 7;                  // owns dims [8*lane, 8*lane+8)
    if (node >= n) return;
    int m = cnt[node]; if (m > CAP) m = CAP;
    const int* cb = col + (size_t)node * CAP;
    const uint4* tb = T_in + lane;
    float4 accA = make_float4(0.f, 0.f, 0.f, 0.f);
    float4 accB = make_float4(0.f, 0.f, 0.f, 0.f);
    int j = 0;
    for (; j + 8 <= m; j += 8) {
        int4 c0 = *(const int4*)&cb[j];
        int4 c1 = *(const int4*)&cb[j + 4];
        uint4 u0 = tb[(size_t)c0.x * 8];
        uint4 u1 = tb[(size_t)c0.y * 8];
        uint4 u2 = tb[(size_t)c0.z * 8];
        uint4 u3 = tb[(size_t)c0.w * 8];
        uint4 u4 = tb[(size_t)c1.x * 8];
        uint4 u5 = tb[(size_t)c1.y * 8];
        uint4 u6 = tb[(size_t)c1.z * 8];
        uint4 u7 = tb[(size_t)c1.w * 8];
        float2 p0 = bf2f(u0.x), p1 = bf2f(u1.x), p2 = bf2f(u2.x), p3 = bf2f(u3.x);
        float2 p4 = bf2f(u4.x), p5 = bf2f(u5.x), p6 = bf2f(u6.x), p7 = bf2f(u7.x);
        accA.x += ((p0.x + p1.x) + (p2.x + p3.x)) + ((p4.x + p5.x) + (p6.x + p7.x));
        accA.y += ((p0.y + p1.y) + (p2.y + p3.y)) + ((p4.y + p5.y) + (p6.y + p7.y));
        float2 q0 = bf2f(u0.y), q1 = bf2f(u1.y), q2 = bf2f(u2.y), q3 = bf2f(u3.y);
        float2 q4 = bf2f(u4.y), q5 = bf2f(u5.y), q6 = bf2f(u6.y), q7 = bf2f(u7.y);
        accA.z += ((q0.x + q1.x) + (q2.x + q3.x)) + ((q4.x + q5.x) + (q6.x + q7.x));
        accA.w += ((q0.y + q1.y) + (q2.y + q3.y)) + ((q4.y + q5.y) + (q6.y + q7.y));
        float2 r0 = bf2f(u0.z), r1 = bf2f(u1.z), r2 = bf2f(u2.z), r3 = bf2f(u3.z);
        float2 r4 = bf2f(u4.z), r5 = bf2f(u5.z), r6 = bf2f(u6.z), r7 = bf2f(u7.z);
        accB.x += ((r0.x + r1.x) + (r2.x + r3.x)) + ((r4.x + r5.x) + (r6.x + r7.x));
        accB.y += ((r0.y + r1.y) + (r2.y + r3.y)) + ((r4.y + r5.y) + (r6.y + r7.y));
        float2 s0 = bf2f(u0.w), s1 = bf2f(u1.w), s2 = bf2f(u2.w), s3 = bf2f(u3.w);
        float2 s4 = bf2f(u4.w), s5 = bf2f(u5.w), s6 = bf2f(u6.w), s7 = bf2f(u7.w);
        accB.z += ((s0.x + s1.x) + (s2.x + s3.x)) + ((s4.x + s5.x) + (s6.x + s7.x));
        accB.w += ((s0.y + s1.y) + (s2.y + s3.y)) + ((s4.y + s5.y) + (s6.y + s7.y));
    }
    for (; j + 4 <= m; j += 4) {
        int4 c0 = *(const int4*)&cb[j];
        uint4 u0 = tb[(size_t)c0.x * 8];
        uint4 u1 = tb[(size_t)c0.y * 8];
        uint4 u2 = tb[(size_t)c0.z * 8];
        uint4 u3 = tb[(size_t)c0.w * 8];
        float2 p0 = bf2f(u0.x), p1 = bf2f(u1.x), p2 = bf2f(u2.x), p3 = bf2f(u3.x);
        accA.x += (p0.x + p1.x) + (p2.x + p3.x);
        accA.y += (p0.y + p1.y) + (p2.y + p3.y);
        float2 q0 = bf2f(u0.y), q1 = bf2f(u1.y), q2 = bf2f(u2.y), q3 = bf2f(u3.y);
        accA.z += (q0.x + q1.x) + (q2.x + q3.x);
        accA.w += (q0.y + q1.y) + (q2.y + q3.y);
        float2 r0 = bf2f(u0.z), r1 = bf2f(u1.z), r2 = bf2f(u2.z), r3 = bf2f(u3.z);
        accB.x += (r0.x + r1.x) + (r2.x + r3.x);
        accB.y += (r0.y + r1.y) + (r2.y + r3.y);
        float2 s0 = bf2f(u0.w), s1 = bf2f(u1.w), s2 = bf2f(u2.w), s3 = bf2f(u3.w);
        accB.z += (s0.x + s1.x) + (s2.x + s3.x);
        accB.w += (s0.y + s1.y) + (s2.y + s3.y);
    }
    for (; j < m; j++) {
        uint4 u = tb[(size_t)cb[j] * 8];
        float2 p = bf2f(u.x), q = bf2f(u.y), r = bf2f(u.z), s = bf2f(u.w);
        accA.x += p.x; accA.y += p.y; accA.z += q.x; accA.w += q.y;
        accB.x += r.x; accB.y += r.y; accB.z += s.x; accB.w += s.y;
    }
    if (FINAL) {
        ((float4*)T_out)[(size_t)node * 16 + lane * 2]     = accA;
        ((float4*)T_out)[(size_t)node * 16 + lane * 2 + 1] = accB;
    } else {
        uint4 o;
        o.x = (uint)bf16r(accA.x) | ((uint)bf16r(accA.y) << 16);
        o.y = (uint)bf16r(accA.z) | ((uint)bf16r(accA.w) << 16);
        o.z = (uint)bf16r(accB.x) | ((uint)bf16r(accB.y) << 16);
        o.w = (uint)bf16r(accB.z) | ((uint)bf16r(accB.w) << 16);
        ((uint4*)T_out)[(size_t)node * 8 + lane] = o;
    }
}

// ---------------- launch ----------------
// ALGEBRAIC COLLAPSE: out = A(A(A X W1)W2)W3 = A^3 . X . (W1 W2 W3)
// Pipeline: [bin(slab-local sort, NO global atomics) + wc]
//           [CSR(slab-run gather) || 8x4 GEMM][agg x3].  No memset needed.

static inline size_t align_up(size_t x, size_t a) { return (x + a - 1) & ~(a - 1); }

extern "C" void kernel_launch(void* const* d_in, const int* in_sizes, int n_in,
                              void* d_out, int out_size, void* d_ws, size_t ws_size,
                              hipStream_t stream) {
    const float* x  = (const float*)d_in[0];
    const int*   ei = (const int*)d_in[1];   // [2, E]
    const float* W1 = (const float*)d_in[2];
    const float* W2 = (const float*)d_in[3];
    const float* W3 = (const float*)d_in[4];
    float* out = (float*)d_out;

    const int N = N_NODES;
    const int E = N_EDGES;
    const int* src = ei;
    const int* dst = ei + E;

    // workspace carve-up (~58 MB)
    char* p = (char*)d_ws;
    int*    cnt   = (int*)p;   p += align_up((size_t)N * 4, 256);
    int*    ofs   = (int*)p;   p += align_up((size_t)NBIN * OFSW * 4, 256);   // 0.4 MB
    uint2*  stage = (uint2*)p; p += align_up((size_t)NBIN * EPB * 8, 256);    // 12.8 MB
    int*    col   = (int*)p;   p += align_up((size_t)N * CAP * 4, 256);       // 19.2 MB
    float*  W23   = (float*)p; p += align_up((size_t)128 * 64 * 4, 256);
    float*  Wc    = (float*)p; p += align_up((size_t)128 * 64 * 4, 256);
    ushort* Y     = (ushort*)p; p += align_up((size_t)N * 64 * 2, 256);  // bf16 node table
    ushort* Za    = (ushort*)p; p += align_up((size_t)N * 64 * 2, 256);  // bf16 ping-pong

    // ---- Pass A: slab-local bin; last block computes Wc = W1 @ (W2 @ W3) ----
    bin_wc<<<NBIN + 1, 256, 0, stream>>>(src, dst, stage, ofs, E,
                                         W1, W2, W3, W23, Wc);

    // ---- Pass B (blocks 0..255) overlapped with Y = X @ Wc (blocks 256..) ----
    const int gemm_blocks = (N + 127) / 128;             // 782
    csr_gemm<<<NBUCK + gemm_blocks, 256, 0, stream>>>(ofs, stage, col, cnt,
                                                      x, Wc, Y, N);

    // ---- out = A^3 Y ----
    const int agg_blocks = (N * 8 + 255) / 256;          // 3125
    agg64<false><<<agg_blocks, 256, 0, stream>>>((const uint4*)Y,  cnt, col, Za, N);
    agg64<false><<<agg_blocks, 256, 0, stream>>>((const uint4*)Za, cnt, col, Y,  N);
    agg64<true ><<<agg_blocks, 256, 0, stream>>>((const uint4*)Y,  cnt, col, out, N);
}

// Round 10
// 254.032 us; speedup vs baseline: 1.0069x; 1.0069x over previous
//
#include <hip/hip_runtime.h>

#define N_NODES 100000
#define N_EDGES 1600000
#define CAP 48      // deg~Poisson(16); P(deg>=48)*N ~ 3e-6 -> no drops
#define NBUCK 256   // dst-range buckets
#define NPB 391     // nodes per bucket = ceil(100000/256)
#define SCAP 8192   // bucket segment capacity
#define NREP 4      // gcur replicas; quarter cap 2048 = mean 1562 + 12 sigma
#define SCAP4 (SCAP / NREP)
#define EPB 4096    // edges per bin block
#define NBIN ((N_EDGES + EPB - 1) / EPB)     // 391

typedef unsigned int uint;
typedef unsigned short ushort;

__device__ __forceinline__ void fma4(float4& c, float s, const float4& w) {
    c.x += s * w.x; c.y += s * w.y; c.z += s * w.z; c.w += s * w.w;
}

__device__ __forceinline__ ushort bf16r(float f) {   // fp32 -> bf16 RNE
    union { float f; uint u; } v; v.f = f;
    return (ushort)((v.u + 0x7fffu + ((v.u >> 16) & 1u)) >> 16);
}

// ---------------- weight collapse: parallel tiny GEMM ----------------
// r10 theory: the single wc block inside bin_wc was the kernel's critical
// path — two SERIAL latency-bound 1-block GEMMs colocated with bin's LDS
// atomic storm (r3 precedent: ~3x stretch) => the invariant ~40 us "bin"
// stall across r1-r9. Extracted here: 16 blocks x 8 rows, per-thread two
// ascending-k length-128 dots (identical summation order -> bit-identical).
__global__ void __launch_bounds__(256) wc_gemm(const float* __restrict__ A,
                                               const float* __restrict__ B,
                                               float* __restrict__ C) {
    // C[128][64] = A[128][128] @ B[128][64]
    const int r = blockIdx.x * 8 + (threadIdx.x >> 5);
    const int c = threadIdx.x & 31;
    float acc0 = 0.f, acc1 = 0.f;
    const float* a = A + r * 128;
#pragma unroll 8
    for (int k = 0; k < 128; k++) {
        float av = a[k];
        acc0 += av * B[k * 64 + c];
        acc1 += av * B[k * 64 + c + 32];
    }
    C[r * 64 + c]      = acc0;
    C[r * 64 + c + 32] = acc1;
}

// ---------------- fp32 GEMM block: 128 rows x 64 cols, 8x4 thread tile --------
// r5: consecutive-rows tiles are structurally bank-conflicted; r7/r8 row-
// interleave kept (rows rg+16*r). r8: residual 126K conflicts are CSR lc
// atomics, not this GEMM — tile closed.
struct alignas(16) GemmSmem {
    float Xs[128][36];   // stride 36: 16B-aligned rows
    float Ws[32][64];
};

template <typename OutT>
__device__ __forceinline__ void gemm64_block(GemmSmem& sm, int bid,
                                             const float* __restrict__ X,
                                             const float* __restrict__ W,
                                             OutT* __restrict__ H, int n) {
    const int tid  = threadIdx.x;
    const int row0 = bid * 128;
    const int rg   = tid >> 4;          // 0..15: rows rg, rg+16, ..., rg+112
    const int cg   = tid & 15;          // col group: cg*4

    float4 acc0[8];
#pragma unroll
    for (int r = 0; r < 8; r++) acc0[r] = make_float4(0.f, 0.f, 0.f, 0.f);

    const int lr = tid >> 1;
    const int lh = tid & 1;
    int grow = row0 + lr; if (grow > n - 1) grow = n - 1;   // clamp tail reads
    const float* gx_base = X + (size_t)grow * 128 + lh * 16;

    for (int k0 = 0; k0 < 128; k0 += 32) {
        const float* gx = gx_base + k0;
#pragma unroll
        for (int i = 0; i < 4; i++)
            *(float4*)&sm.Xs[lr][lh * 16 + 4 * i] = *(const float4*)(gx + 4 * i);
        const float4* gw = (const float4*)(W + (size_t)k0 * 64);
        float4* sw = (float4*)&sm.Ws[0][0];
#pragma unroll
        for (int i = 0; i < 2; i++) sw[tid + 256 * i] = gw[tid + 256 * i];
        __syncthreads();

#pragma unroll
        for (int kk = 0; kk < 32; kk += 4) {
            float4 w00 = *(const float4*)&sm.Ws[kk + 0][cg * 4];
            float4 w01 = *(const float4*)&sm.Ws[kk + 1][cg * 4];
            float4 w02 = *(const float4*)&sm.Ws[kk + 2][cg * 4];
            float4 w03 = *(const float4*)&sm.Ws[kk + 3][cg * 4];
#pragma unroll
            for (int r = 0; r < 8; r++) {
                float4 a = *(const float4*)&sm.Xs[rg + 16 * r][kk];
                fma4(acc0[r], a.x, w00);
                fma4(acc0[r], a.y, w01);
                fma4(acc0[r], a.z, w02);
                fma4(acc0[r], a.w, w03);
            }
        }
        __syncthreads();
    }

#pragma unroll
    for (int r = 0; r < 8; r++) {
        int row = row0 + rg + 16 * r;
        if (row < n) {
            if constexpr (sizeof(OutT) == 2) {   // bf16 epilogue, node-major
                ushort4 o0 = make_ushort4(bf16r(acc0[r].x), bf16r(acc0[r].y),
                                          bf16r(acc0[r].z), bf16r(acc0[r].w));
                *(ushort4*)&H[(size_t)row * 64 + cg * 4] = o0;
            } else {
                *(float4*)&H[(size_t)row * 64 + cg * 4] = *(float4*)&acc0[r];
            }
        }
    }
}

// ---------------- Pass A: edge binning (r8 layout, wc block removed) ----------
// LDS hist (slot in reg) -> exclusive scan -> LDS bucket-sort -> coalesced
// writeout into this block's replica quarter of each bucket segment.
struct BinSmem {
    int ecnt[NBUCK];
    int base[NBUCK];
    int lofs[NBUCK];
    uint2 estage[EPB];   // 32 KB bucket-sorted staging
};

__global__ void __launch_bounds__(256) bin_edges(const int* __restrict__ src,
                                                 const int* __restrict__ dst,
                                                 int* __restrict__ gcur,
                                                 uint2* __restrict__ seg, int E) {
    __shared__ BinSmem sh;
    const int t = threadIdx.x;
    sh.ecnt[t] = 0;                          // t spans exactly NBUCK
    __syncthreads();
    const int e0 = blockIdx.x * EPB;
    const int rep = blockIdx.x & (NREP - 1); // replica counter set for this block
    uint sreg[EPB / 256];
    int  dreg[EPB / 256];
    int  slreg[EPB / 256];
    // phase 1: LDS histogram; returned value IS this edge's in-bucket slot
#pragma unroll
    for (int k = 0; k < EPB / 256; k++) {
        int i = e0 + k * 256 + t;
        if (i < E) {
            int d = dst[i];
            sreg[k] = (uint)src[i];
            dreg[k] = d;
            slreg[k] = atomicAdd(&sh.ecnt[d / NPB], 1);
        }
    }
    __syncthreads();
    // phase 2a: one reserving atomic per non-empty bucket on this replica word
    const int c = sh.ecnt[t];
    sh.base[t] = (c > 0) ? atomicAdd(&gcur[rep * NBUCK + t], c) : 0;
    // phase 2b: exclusive scan of ecnt -> lofs (Hillis-Steele over 256)
    sh.lofs[t] = c;
    __syncthreads();
#pragma unroll
    for (int off = 1; off < NBUCK; off <<= 1) {
        int u = (t >= off) ? sh.lofs[t - off] : 0;
        __syncthreads();
        sh.lofs[t] += u;
        __syncthreads();
    }
    const int excl = sh.lofs[t] - c;         // inclusive -> exclusive
    __syncthreads();
    sh.lofs[t] = excl;
    __syncthreads();
    // phase 3a: stage edges bucket-sorted in LDS
#pragma unroll
    for (int k = 0; k < EPB / 256; k++) {
        int i = e0 + k * 256 + t;
        if (i < E) {
            int b = dreg[k] / NPB;
            sh.estage[sh.lofs[b] + slreg[k]] =
                make_uint2(sreg[k], (uint)dreg[k]);
        }
    }
    __syncthreads();
    // phase 3b: coalesced write-out into this block's replica quarter
    const int total = min(E - e0, EPB);
    for (int i = t; i < total; i += 256) {
        uint2 e = sh.estage[i];
        int b = (int)e.y / NPB;
        int s = sh.base[b] + (i - sh.lofs[b]);
        if (s < SCAP4)
            seg[(size_t)b * SCAP + rep * SCAP4 + s] = e;
    }
}

// ---------------- Pass B + main GEMM (fused, heterogeneous blocks) ----------------
// CSR build (global-scatter/latency-bound, light LDS) overlapped with
// Y = X @ Wc (LDS/VALU-bound) — pipe-disjoint pairing (round-1 proven).
union CsrGemmSmem {
    int lc[NPB];
    GemmSmem g;
};

__global__ void __launch_bounds__(256, 3) csr_gemm(const int* __restrict__ gcur,
                                                   const uint2* __restrict__ seg,
                                                   int* __restrict__ col,
                                                   int* __restrict__ cnt,
                                                   const float* __restrict__ X,
                                                   const float* __restrict__ Wc,
                                                   ushort* __restrict__ Y, int n) {
    __shared__ CsrGemmSmem sh;
    if (blockIdx.x < NBUCK) {
        const int b = blockIdx.x;
        const int t = threadIdx.x;
        for (int i = t; i < NPB; i += 256) sh.lc[i] = 0;
        __syncthreads();
        const int node0 = b * NPB;
#pragma unroll
        for (int q = 0; q < NREP; q++) {
            int m = gcur[q * NBUCK + b]; if (m > SCAP4) m = SCAP4;
            const uint2* sg = seg + (size_t)b * SCAP + q * SCAP4;
            for (int i = t; i < m; i += 256) {
                uint2 e = sg[i];
                int d = (int)e.y;
                int slot = atomicAdd(&sh.lc[d - node0], 1);
                if (slot < CAP) col[(size_t)d * CAP + slot] = (int)e.x;
            }
        }
        __syncthreads();
        for (int i = t; i < NPB; i += 256) {
            int node = node0 + i;
            if (node < n) cnt[node] = (sh.lc[i] > CAP) ? CAP : sh.lc[i];
        }
    } else {
        gemm64_block<ushort>(sh.g, blockIdx.x - NBUCK, X, Wc, Y, n);
    }
}

// ---------------- Aggregation, width 64, bf16 table [N][64] ----------------
// 8 lanes per node; lane owns a uint4 (8 dims) -> one coalesced 128 B
// (exactly one cacheline) gather per edge. r2: no dim-split. At the
// random-gather MALL service floor; lane-shape neutral (r4).
__device__ __forceinline__ float2 bf2f(uint u) {
    union { uint u; float f; } a, b;
    a.u = u << 16; b.u = u & 0xffff0000u;
    return make_float2(a.f, b.f);
}

template <bool FINAL>
__global__ void __launch_bounds__(256) agg64(const uint4* __restrict__ T_in,
                                             const int* __restrict__ cnt,
                                             const int* __restrict__ col,
                                             void* __restrict__ T_out, int n) {
    int gid  = blockIdx.x * blockDim.x + threadIdx.x;
    int node = gid >> 3;
    int lane = gid & 7;                  // owns dims [8*lane, 8*lane+8)
    if (node >= n) return;
    int m = cnt[node]; if (m > CAP) m = CAP;
    const int* cb = col + (size_t)node * CAP;
    const uint4* tb = T_in + lane;
    float4 accA = make_float4(0.f, 0.f, 0.f, 0.f);
    float4 accB = make_float4(0.f, 0.f, 0.f, 0.f);
    int j = 0;
    for (; j + 8 <= m; j += 8) {
        int4 c0 = *(const int4*)&cb[j];
        int4 c1 = *(const int4*)&cb[j + 4];
        uint4 u0 = tb[(size_t)c0.x * 8];
        uint4 u1 = tb[(size_t)c0.y * 8];
        uint4 u2 = tb[(size_t)c0.z * 8];
        uint4 u3 = tb[(size_t)c0.w * 8];
        uint4 u4 = tb[(size_t)c1.x * 8];
        uint4 u5 = tb[(size_t)c1.y * 8];
        uint4 u6 = tb[(size_t)c1.z * 8];
        uint4 u7 = tb[(size_t)c1.w * 8];
        float2 p0 = bf2f(u0.x), p1 = bf2f(u1.x), p2 = bf2f(u2.x), p3 = bf2f(u3.x);
        float2 p4 = bf2f(u4.x), p5 = bf2f(u5.x), p6 = bf2f(u6.x), p7 = bf2f(u7.x);
        accA.x += ((p0.x + p1.x) + (p2.x + p3.x)) + ((p4.x + p5.x) + (p6.x + p7.x));
        accA.y += ((p0.y + p1.y) + (p2.y + p3.y)) + ((p4.y + p5.y) + (p6.y + p7.y));
        float2 q0 = bf2f(u0.y), q1 = bf2f(u1.y), q2 = bf2f(u2.y), q3 = bf2f(u3.y);
        float2 q4 = bf2f(u4.y), q5 = bf2f(u5.y), q6 = bf2f(u6.y), q7 = bf2f(u7.y);
        accA.z += ((q0.x + q1.x) + (q2.x + q3.x)) + ((q4.x + q5.x) + (q6.x + q7.x));
        accA.w += ((q0.y + q1.y) + (q2.y + q3.y)) + ((q4.y + q5.y) + (q6.y + q7.y));
        float2 r0 = bf2f(u0.z), r1 = bf2f(u1.z), r2 = bf2f(u2.z), r3 = bf2f(u3.z);
        float2 r4 = bf2f(u4.z), r5 = bf2f(u5.z), r6 = bf2f(u6.z), r7 = bf2f(u7.z);
        accB.x += ((r0.x + r1.x) + (r2.x + r3.x)) + ((r4.x + r5.x) + (r6.x + r7.x));
        accB.y += ((r0.y + r1.y) + (r2.y + r3.y)) + ((r4.y + r5.y) + (r6.y + r7.y));
        float2 s0 = bf2f(u0.w), s1 = bf2f(u1.w), s2 = bf2f(u2.w), s3 = bf2f(u3.w);
        float2 s4 = bf2f(u4.w), s5 = bf2f(u5.w), s6 = bf2f(u6.w), s7 = bf2f(u7.w);
        accB.z += ((s0.x + s1.x) + (s2.x + s3.x)) + ((s4.x + s5.x) + (s6.x + s7.x));
        accB.w += ((s0.y + s1.y) + (s2.y + s3.y)) + ((s4.y + s5.y) + (s6.y + s7.y));
    }
    for (; j + 4 <= m; j += 4) {
        int4 c0 = *(const int4*)&cb[j];
        uint4 u0 = tb[(size_t)c0.x * 8];
        uint4 u1 = tb[(size_t)c0.y * 8];
        uint4 u2 = tb[(size_t)c0.z * 8];
        uint4 u3 = tb[(size_t)c0.w * 8];
        float2 p0 = bf2f(u0.x), p1 = bf2f(u1.x), p2 = bf2f(u2.x), p3 = bf2f(u3.x);
        accA.x += (p0.x + p1.x) + (p2.x + p3.x);
        accA.y += (p0.y + p1.y) + (p2.y + p3.y);
        float2 q0 = bf2f(u0.y), q1 = bf2f(u1.y), q2 = bf2f(u2.y), q3 = bf2f(u3.y);
        accA.z += (q0.x + q1.x) + (q2.x + q3.x);
        accA.w += (q0.y + q1.y) + (q2.y + q3.y);
        float2 r0 = bf2f(u0.z), r1 = bf2f(u1.z), r2 = bf2f(u2.z), r3 = bf2f(u3.z);
        accB.x += (r0.x + r1.x) + (r2.x + r3.x);
        accB.y += (r0.y + r1.y) + (r2.y + r3.y);
        float2 s0 = bf2f(u0.w), s1 = bf2f(u1.w), s2 = bf2f(u2.w), s3 = bf2f(u3.w);
        accB.z += (s0.x + s1.x) + (s2.x + s3.x);
        accB.w += (s0.y + s1.y) + (s2.y + s3.y);
    }
    for (; j < m; j++) {
        uint4 u = tb[(size_t)cb[j] * 8];
        float2 p = bf2f(u.x), q = bf2f(u.y), r = bf2f(u.z), s = bf2f(u.w);
        accA.x += p.x; accA.y += p.y; accA.z += q.x; accA.w += q.y;
        accB.x += r.x; accB.y += r.y; accB.z += s.x; accB.w += s.y;
    }
    if (FINAL) {
        ((float4*)T_out)[(size_t)node * 16 + lane * 2]     = accA;
        ((float4*)T_out)[(size_t)node * 16 + lane * 2 + 1] = accB;
    } else {
        uint4 o;
        o.x = (uint)bf16r(accA.x) | ((uint)bf16r(accA.y) << 16);
        o.y = (uint)bf16r(accA.z) | ((uint)bf16r(accA.w) << 16);
        o.z = (uint)bf16r(accB.x) | ((uint)bf16r(accB.y) << 16);
        o.w = (uint)bf16r(accB.z) | ((uint)bf16r(accB.w) << 16);
        ((uint4*)T_out)[(size_t)node * 8 + lane] = o;
    }
}

// ---------------- launch ----------------
// ALGEBRAIC COLLAPSE: out = A(A(A X W1)W2)W3 = A^3 . X . (W1 W2 W3)
// Pipeline: [wc1][wc2][bin (r8 layout, no wc block)][CSR || GEMM][agg x3].
// r10: weight collapse extracted from bin into two parallel 16-block kernels
// — testing the theory that the colocated serial wc block was the invariant
// ~40 us critical path of every bin variant (r1-r9).

static inline size_t align_up(size_t x, size_t a) { return (x + a - 1) & ~(a - 1); }

extern "C" void kernel_launch(void* const* d_in, const int* in_sizes, int n_in,
                              void* d_out, int out_size, void* d_ws, size_t ws_size,
                              hipStream_t stream) {
    const float* x  = (const float*)d_in[0];
    const int*   ei = (const int*)d_in[1];   // [2, E]
    const float* W1 = (const float*)d_in[2];
    const float* W2 = (const float*)d_in[3];
    const float* W3 = (const float*)d_in[4];
    float* out = (float*)d_out;

    const int N = N_NODES;
    const int E = N_EDGES;
    const int* src = ei;
    const int* dst = ei + E;

    // workspace carve-up (~63 MB)
    char* p = (char*)d_ws;
    int*    gcur = (int*)p;   p += align_up((size_t)NREP * NBUCK * 4, 256);
    int*    cnt  = (int*)p;   p += align_up((size_t)N * 4, 256);
    uint2*  seg  = (uint2*)p; p += align_up((size_t)NBUCK * SCAP * 8, 256);  // 16.8 MB
    int*    col  = (int*)p;   p += align_up((size_t)N * CAP * 4, 256);       // 19.2 MB
    float*  W23  = (float*)p; p += align_up((size_t)128 * 64 * 4, 256);
    float*  Wc   = (float*)p; p += align_up((size_t)128 * 64 * 4, 256);
    ushort* Y    = (ushort*)p; p += align_up((size_t)N * 64 * 2, 256);  // bf16 node table
    ushort* Za   = (ushort*)p; p += align_up((size_t)N * 64 * 2, 256);  // bf16 ping-pong

    hipMemsetAsync(gcur, 0, (size_t)NREP * NBUCK * 4, stream);

    // ---- weight collapse: Wc = W1 @ (W2 @ W3), two parallel tiny kernels ----
    wc_gemm<<<16, 256, 0, stream>>>(W2, W3, W23);
    wc_gemm<<<16, 256, 0, stream>>>(W1, W23, Wc);

    // ---- Pass A: bin edges (pure; no wc block) ----
    bin_edges<<<NBIN, 256, 0, stream>>>(src, dst, gcur, seg, E);

    // ---- Pass B (blocks 0..255) overlapped with Y = X @ Wc (blocks 256..) ----
    const int gemm_blocks = (N + 127) / 128;             // 782
    csr_gemm<<<NBUCK + gemm_blocks, 256, 0, stream>>>(gcur, seg, col, cnt,
                                                      x, Wc, Y, N);

    // ---- out = A^3 Y ----
    const int agg_blocks = (N * 8 + 255) / 256;          // 3125
    agg64<false><<<agg_blocks, 256, 0, stream>>>((const uint4*)Y,  cnt, col, Za, N);
    agg64<false><<<agg_blocks, 256, 0, stream>>>((const uint4*)Za, cnt, col, Y,  N);
    agg64<true ><<<agg_blocks, 256, 0, stream>>>((const uint4*)Y,  cnt, col, out, N);
}

// Round 11
// 242.878 us; speedup vs baseline: 1.0531x; 1.0459x over previous
//
#include <hip/hip_runtime.h>

#define N_NODES 100000
#define N_EDGES 1600000
#define CAP 48      // deg~Poisson(16); P(deg>=48)*N ~ 3e-6 -> no drops
#define NBUCK 256   // dst-range buckets
#define NPB 391     // nodes per bucket = ceil(100000/256)
#define SCAP 8192   // bucket segment capacity (also packed-col bucket region)
#define NREP 4      // gcur replicas; quarter cap 2048 = mean 1562 + 12 sigma
#define SCAP4 (SCAP / NREP)
#define EPB 4096    // edges per bin block
#define NBIN ((N_EDGES + EPB - 1) / EPB)     // 391

typedef unsigned int uint;
typedef unsigned short ushort;

__device__ __forceinline__ void fma4(float4& c, float s, const float4& w) {
    c.x += s * w.x; c.y += s * w.y; c.z += s * w.z; c.w += s * w.w;
}

__device__ __forceinline__ ushort bf16r(float f) {   // fp32 -> bf16 RNE
    union { float f; uint u; } v; v.f = f;
    return (ushort)((v.u + 0x7fffu + ((v.u >> 16) & 1u)) >> 16);
}

// ---------------- fp32 GEMM block: 128 rows x 64 cols, 8x4 thread tile --------
// r5/r7/r8: row-interleaved tile (rows rg+16*r); conflicts were CSR atomics,
// not this GEMM — tile closed.
struct alignas(16) GemmSmem {
    float Xs[128][36];   // stride 36: 16B-aligned rows
    float Ws[32][64];
};

template <typename OutT>
__device__ __forceinline__ void gemm64_block(GemmSmem& sm, int bid,
                                             const float* __restrict__ X,
                                             const float* __restrict__ W,
                                             OutT* __restrict__ H, int n) {
    const int tid  = threadIdx.x;
    const int row0 = bid * 128;
    const int rg   = tid >> 4;          // 0..15: rows rg, rg+16, ..., rg+112
    const int cg   = tid & 15;          // col group: cg*4

    float4 acc0[8];
#pragma unroll
    for (int r = 0; r < 8; r++) acc0[r] = make_float4(0.f, 0.f, 0.f, 0.f);

    const int lr = tid >> 1;
    const int lh = tid & 1;
    int grow = row0 + lr; if (grow > n - 1) grow = n - 1;   // clamp tail reads
    const float* gx_base = X + (size_t)grow * 128 + lh * 16;

    for (int k0 = 0; k0 < 128; k0 += 32) {
        const float* gx = gx_base + k0;
#pragma unroll
        for (int i = 0; i < 4; i++)
            *(float4*)&sm.Xs[lr][lh * 16 + 4 * i] = *(const float4*)(gx + 4 * i);
        const float4* gw = (const float4*)(W + (size_t)k0 * 64);
        float4* sw = (float4*)&sm.Ws[0][0];
#pragma unroll
        for (int i = 0; i < 2; i++) sw[tid + 256 * i] = gw[tid + 256 * i];
        __syncthreads();

#pragma unroll
        for (int kk = 0; kk < 32; kk += 4) {
            float4 w00 = *(const float4*)&sm.Ws[kk + 0][cg * 4];
            float4 w01 = *(const float4*)&sm.Ws[kk + 1][cg * 4];
            float4 w02 = *(const float4*)&sm.Ws[kk + 2][cg * 4];
            float4 w03 = *(const float4*)&sm.Ws[kk + 3][cg * 4];
#pragma unroll
            for (int r = 0; r < 8; r++) {
                float4 a = *(const float4*)&sm.Xs[rg + 16 * r][kk];
                fma4(acc0[r], a.x, w00);
                fma4(acc0[r], a.y, w01);
                fma4(acc0[r], a.z, w02);
                fma4(acc0[r], a.w, w03);
            }
        }
        __syncthreads();
    }

#pragma unroll
    for (int r = 0; r < 8; r++) {
        int row = row0 + rg + 16 * r;
        if (row < n) {
            if constexpr (sizeof(OutT) == 2) {   // bf16 epilogue, node-major
                ushort4 o0 = make_ushort4(bf16r(acc0[r].x), bf16r(acc0[r].y),
                                          bf16r(acc0[r].z), bf16r(acc0[r].w));
                *(ushort4*)&H[(size_t)row * 64 + cg * 4] = o0;
            } else {
                *(float4*)&H[(size_t)row * 64 + cg * 4] = *(float4*)&acc0[r];
            }
        }
    }
}

// ---------------- Pass A + weight collapse (r8 layout, best known) ----------
union BinWcSmem {
    struct {
        int ecnt[NBUCK];
        int base[NBUCK];
        int lofs[NBUCK];
        uint2 estage[EPB];   // 32 KB bucket-sorted staging
    } b;                     // 35.8 KB
    GemmSmem g;              // 26.6 KB
};

__global__ void __launch_bounds__(256) bin_wc(const int* __restrict__ src,
                                              const int* __restrict__ dst,
                                              int* __restrict__ gcur,
                                              uint2* __restrict__ seg, int E,
                                              const float* __restrict__ W1,
                                              const float* __restrict__ W2,
                                              const float* __restrict__ W3,
                                              float* __restrict__ W23,
                                              float* __restrict__ Wc) {
    __shared__ BinWcSmem sh;
    if (blockIdx.x == gridDim.x - 1) {      // weight-collapse block
        gemm64_block<float>(sh.g, 0, W2, W3, W23, 128);
        __syncthreads();                     // W23 global writes visible in-block
        gemm64_block<float>(sh.g, 0, W1, W23, Wc, 128);
        return;
    }
    const int t = threadIdx.x;
    sh.b.ecnt[t] = 0;                        // t spans exactly NBUCK
    __syncthreads();
    const int e0 = blockIdx.x * EPB;
    const int rep = blockIdx.x & (NREP - 1); // replica counter set for this block
    uint sreg[EPB / 256];
    int  dreg[EPB / 256];
    int  slreg[EPB / 256];
    // phase 1: LDS histogram; returned value IS this edge's in-bucket slot
#pragma unroll
    for (int k = 0; k < EPB / 256; k++) {
        int i = e0 + k * 256 + t;
        if (i < E) {
            int d = dst[i];
            sreg[k] = (uint)src[i];
            dreg[k] = d;
            slreg[k] = atomicAdd(&sh.b.ecnt[d / NPB], 1);
        }
    }
    __syncthreads();
    // phase 2a: one reserving atomic per non-empty bucket on this replica word
    const int c = sh.b.ecnt[t];
    sh.b.base[t] = (c > 0) ? atomicAdd(&gcur[rep * NBUCK + t], c) : 0;
    // phase 2b: exclusive scan of ecnt -> lofs (Hillis-Steele over 256)
    sh.b.lofs[t] = c;
    __syncthreads();
#pragma unroll
    for (int off = 1; off < NBUCK; off <<= 1) {
        int u = (t >= off) ? sh.b.lofs[t - off] : 0;
        __syncthreads();
        sh.b.lofs[t] += u;
        __syncthreads();
    }
    const int excl = sh.b.lofs[t] - c;       // inclusive -> exclusive
    __syncthreads();
    sh.b.lofs[t] = excl;
    __syncthreads();
    // phase 3a: stage edges bucket-sorted in LDS
#pragma unroll
    for (int k = 0; k < EPB / 256; k++) {
        int i = e0 + k * 256 + t;
        if (i < E) {
            int b = dreg[k] / NPB;
            sh.b.estage[sh.b.lofs[b] + slreg[k]] =
                make_uint2(sreg[k], (uint)dreg[k]);
        }
    }
    __syncthreads();
    // phase 3b: coalesced write-out into this block's replica quarter
    const int total = min(E - e0, EPB);
    for (int i = t; i < total; i += 256) {
        uint2 e = sh.b.estage[i];
        int b = (int)e.y / NPB;
        int s = sh.b.base[b] + (i - sh.b.lofs[b]);
        if (s < SCAP4)
            seg[(size_t)b * SCAP + rep * SCAP4 + s] = e;
    }
}

// ---------------- Pass B + main GEMM (fused, heterogeneous blocks) ----------------
// r11 change: PACKED CSR. Per bucket: counting-sort by dst — pass A counts
// per-node degrees from seg, LDS scan builds 4-aligned per-node offsets,
// pass B places src packed at col[b*SCAP + lrp[d] + slot]. Consecutive
// nodes' lists become line-adjacent: agg's col reads drop from ~2 lines/node
// (CAP-strided 19.2 MB) to ~0.5 line/node (packed 8.4 MB, MALL-resident).
union CsrGemmSmem {
    struct {
        int lc[NPB];
        int lrp[NPB];
        int sc[2][512];   // ping-pong scan buffer
    } c;                  // ~7.2 KB
    GemmSmem g;           // 26.6 KB
};

__global__ void __launch_bounds__(256, 3) csr_gemm(const int* __restrict__ gcur,
                                                   const uint2* __restrict__ seg,
                                                   int* __restrict__ col,
                                                   int* __restrict__ cnt,
                                                   int* __restrict__ rowptr,
                                                   const float* __restrict__ X,
                                                   const float* __restrict__ Wc,
                                                   ushort* __restrict__ Y, int n) {
    __shared__ CsrGemmSmem sh;
    if (blockIdx.x < NBUCK) {
        const int b = blockIdx.x;
        const int t = threadIdx.x;
        const int node0 = b * NPB;
        for (int i = t; i < NPB; i += 256) sh.c.lc[i] = 0;
        __syncthreads();
        // pass A: per-node degree counts from the 4 seg quarters
#pragma unroll
        for (int q = 0; q < NREP; q++) {
            int m = gcur[q * NBUCK + b]; if (m > SCAP4) m = SCAP4;
            const uint2* sg = seg + (size_t)b * SCAP + q * SCAP4;
            for (int i = t; i < m; i += 256)
                atomicAdd(&sh.c.lc[(int)sg[i].y - node0], 1);
        }
        __syncthreads();
        // scan of 4-rounded counts (Hillis-Steele over 512, 2 elems/thread)
        sh.c.sc[0][t]       = (t < NPB) ? ((sh.c.lc[t] + 3) & ~3) : 0;
        sh.c.sc[0][t + 256] = (t + 256 < NPB) ? ((sh.c.lc[t + 256] + 3) & ~3) : 0;
        __syncthreads();
        int pb = 0;
#pragma unroll
        for (int off = 1; off < 512; off <<= 1) {
            int a0 = sh.c.sc[pb][t];
            int a1 = sh.c.sc[pb][t + 256];
            int b0 = (t >= off) ? sh.c.sc[pb][t - off] : 0;
            int b1 = (t + 256 >= off) ? sh.c.sc[pb][t + 256 - off] : 0;
            sh.c.sc[pb ^ 1][t]       = a0 + b0;
            sh.c.sc[pb ^ 1][t + 256] = a1 + b1;
            __syncthreads();
            pb ^= 1;
        }
        // exclusive offsets (4-aligned); re-zero lc for placement pass
        if (t < NPB)
            sh.c.lrp[t] = sh.c.sc[pb][t] - ((sh.c.lc[t] + 3) & ~3);
        if (t + 256 < NPB)
            sh.c.lrp[t + 256] = sh.c.sc[pb][t + 256] - ((sh.c.lc[t + 256] + 3) & ~3);
        __syncthreads();
        for (int i = t; i < NPB; i += 256) sh.c.lc[i] = 0;
        __syncthreads();
        // pass B: place src packed
#pragma unroll
        for (int q = 0; q < NREP; q++) {
            int m = gcur[q * NBUCK + b]; if (m > SCAP4) m = SCAP4;
            const uint2* sg = seg + (size_t)b * SCAP + q * SCAP4;
            for (int i = t; i < m; i += 256) {
                uint2 e = sg[i];
                int dn = (int)e.y - node0;
                int slot = atomicAdd(&sh.c.lc[dn], 1);
                int pos = sh.c.lrp[dn] + slot;
                if (pos < SCAP) col[(size_t)b * SCAP + pos] = (int)e.x;
            }
        }
        __syncthreads();
        // publish cnt (capped) + absolute rowptr, coalesced
        for (int i = t; i < NPB; i += 256) {
            int node = node0 + i;
            if (node < n) {
                int c = sh.c.lc[i];
                cnt[node] = (c > CAP) ? CAP : c;
                rowptr[node] = b * SCAP + sh.c.lrp[i];
            }
        }
    } else {
        gemm64_block<ushort>(sh.g, blockIdx.x - NBUCK, X, Wc, Y, n);
    }
}

// ---------------- Aggregation, width 64, bf16 table [N][64] ----------------
// 8 lanes per node; lane owns a uint4 (8 dims) -> one coalesced 128 B
// (exactly one cacheline) gather per edge. r2: no dim-split. r11: packed
// col via rowptr (16 B-aligned by construction).
__device__ __forceinline__ float2 bf2f(uint u) {
    union { uint u; float f; } a, b;
    a.u = u << 16; b.u = u & 0xffff0000u;
    return make_float2(a.f, b.f);
}

template <bool FINAL>
__global__ void __launch_bounds__(256) agg64(const uint4* __restrict__ T_in,
                                             const int* __restrict__ cnt,
                                             const int* __restrict__ col,
                                             const int* __restrict__ rowptr,
                                             void* __restrict__ T_out, int n) {
    int gid  = blockIdx.x * blockDim.x + threadIdx.x;
    int node = gid >> 3;
    int lane = gid & 7;                  // owns dims [8*lane, 8*lane+8)
    if (node >= n) return;
    int m = cnt[node]; if (m > CAP) m = CAP;
    const int* cb = col + rowptr[node];
    const uint4* tb = T_in + lane;
    float4 accA = make_float4(0.f, 0.f, 0.f, 0.f);
    float4 accB = make_float4(0.f, 0.f, 0.f, 0.f);
    int j = 0;
    for (; j + 8 <= m; j += 8) {
        int4 c0 = *(const int4*)&cb[j];
        int4 c1 = *(const int4*)&cb[j + 4];
        uint4 u0 = tb[(size_t)c0.x * 8];
        uint4 u1 = tb[(size_t)c0.y * 8];
        uint4 u2 = tb[(size_t)c0.z * 8];
        uint4 u3 = tb[(size_t)c0.w * 8];
        uint4 u4 = tb[(size_t)c1.x * 8];
        uint4 u5 = tb[(size_t)c1.y * 8];
        uint4 u6 = tb[(size_t)c1.z * 8];
        uint4 u7 = tb[(size_t)c1.w * 8];
        float2 p0 = bf2f(u0.x), p1 = bf2f(u1.x), p2 = bf2f(u2.x), p3 = bf2f(u3.x);
        float2 p4 = bf2f(u4.x), p5 = bf2f(u5.x), p6 = bf2f(u6.x), p7 = bf2f(u7.x);
        accA.x += ((p0.x + p1.x) + (p2.x + p3.x)) + ((p4.x + p5.x) + (p6.x + p7.x));
        accA.y += ((p0.y + p1.y) + (p2.y + p3.y)) + ((p4.y + p5.y) + (p6.y + p7.y));
        float2 q0 = bf2f(u0.y), q1 = bf2f(u1.y), q2 = bf2f(u2.y), q3 = bf2f(u3.y);
        float2 q4 = bf2f(u4.y), q5 = bf2f(u5.y), q6 = bf2f(u6.y), q7 = bf2f(u7.y);
        accA.z += ((q0.x + q1.x) + (q2.x + q3.x)) + ((q4.x + q5.x) + (q6.x + q7.x));
        accA.w += ((q0.y + q1.y) + (q2.y + q3.y)) + ((q4.y + q5.y) + (q6.y + q7.y));
        float2 r0 = bf2f(u0.z), r1 = bf2f(u1.z), r2 = bf2f(u2.z), r3 = bf2f(u3.z);
        float2 r4 = bf2f(u4.z), r5 = bf2f(u5.z), r6 = bf2f(u6.z), r7 = bf2f(u7.z);
        accB.x += ((r0.x + r1.x) + (r2.x + r3.x)) + ((r4.x + r5.x) + (r6.x + r7.x));
        accB.y += ((r0.y + r1.y) + (r2.y + r3.y)) + ((r4.y + r5.y) + (r6.y + r7.y));
        float2 s0 = bf2f(u0.w), s1 = bf2f(u1.w), s2 = bf2f(u2.w), s3 = bf2f(u3.w);
        float2 s4 = bf2f(u4.w), s5 = bf2f(u5.w), s6 = bf2f(u6.w), s7 = bf2f(u7.w);
        accB.z += ((s0.x + s1.x) + (s2.x + s3.x)) + ((s4.x + s5.x) + (s6.x + s7.x));
        accB.w += ((s0.y + s1.y) + (s2.y + s3.y)) + ((s4.y + s5.y) + (s6.y + s7.y));
    }
    for (; j + 4 <= m; j += 4) {
        int4 c0 = *(const int4*)&cb[j];
        uint4 u0 = tb[(size_t)c0.x * 8];
        uint4 u1 = tb[(size_t)c0.y * 8];
        uint4 u2 = tb[(size_t)c0.z * 8];
        uint4 u3 = tb[(size_t)c0.w * 8];
        float2 p0 = bf2f(u0.x), p1 = bf2f(u1.x), p2 = bf2f(u2.x), p3 = bf2f(u3.x);
        accA.x += (p0.x + p1.x) + (p2.x + p3.x);
        accA.y += (p0.y + p1.y) + (p2.y + p3.y);
        float2 q0 = bf2f(u0.y), q1 = bf2f(u1.y), q2 = bf2f(u2.y), q3 = bf2f(u3.y);
        accA.z += (q0.x + q1.x) + (q2.x + q3.x);
        accA.w += (q0.y + q1.y) + (q2.y + q3.y);
        float2 r0 = bf2f(u0.z), r1 = bf2f(u1.z), r2 = bf2f(u2.z), r3 = bf2f(u3.z);
        accB.x += (r0.x + r1.x) + (r2.x + r3.x);
        accB.y += (r0.y + r1.y) + (r2.y + r3.y);
        float2 s0 = bf2f(u0.w), s1 = bf2f(u1.w), s2 = bf2f(u2.w), s3 = bf2f(u3.w);
        accB.z += (s0.x + s1.x) + (s2.x + s3.x);
        accB.w += (s0.y + s1.y) + (s2.y + s3.y);
    }
    for (; j < m; j++) {
        uint4 u = tb[(size_t)cb[j] * 8];
        float2 p = bf2f(u.x), q = bf2f(u.y), r = bf2f(u.z), s = bf2f(u.w);
        accA.x += p.x; accA.y += p.y; accA.z += q.x; accA.w += q.y;
        accB.x += r.x; accB.y += r.y; accB.z += s.x; accB.w += s.y;
    }
    if (FINAL) {
        ((float4*)T_out)[(size_t)node * 16 + lane * 2]     = accA;
        ((float4*)T_out)[(size_t)node * 16 + lane * 2 + 1] = accB;
    } else {
        uint4 o;
        o.x = (uint)bf16r(accA.x) | ((uint)bf16r(accA.y) << 16);
        o.y = (uint)bf16r(accA.z) | ((uint)bf16r(accA.w) << 16);
        o.z = (uint)bf16r(accB.x) | ((uint)bf16r(accB.y) << 16);
        o.w = (uint)bf16r(accB.z) | ((uint)bf16r(accB.w) << 16);
        ((uint4*)T_out)[(size_t)node * 8 + lane] = o;
    }
}

// ---------------- launch ----------------
// ALGEBRAIC COLLAPSE: out = A(A(A X W1)W2)W3 = A^3 . X . (W1 W2 W3)
// Pipeline (r8 base + packed CSR): [bin+wc][packed-CSR || GEMM][agg x3].

static inline size_t align_up(size_t x, size_t a) { return (x + a - 1) & ~(a - 1); }

extern "C" void kernel_launch(void* const* d_in, const int* in_sizes, int n_in,
                              void* d_out, int out_size, void* d_ws, size_t ws_size,
                              hipStream_t stream) {
    const float* x  = (const float*)d_in[0];
    const int*   ei = (const int*)d_in[1];   // [2, E]
    const float* W1 = (const float*)d_in[2];
    const float* W2 = (const float*)d_in[3];
    const float* W3 = (const float*)d_in[4];
    float* out = (float*)d_out;

    const int N = N_NODES;
    const int E = N_EDGES;
    const int* src = ei;
    const int* dst = ei + E;

    // workspace carve-up (~53 MB)
    char* p = (char*)d_ws;
    int*    gcur   = (int*)p;   p += align_up((size_t)NREP * NBUCK * 4, 256);
    int*    cnt    = (int*)p;   p += align_up((size_t)N * 4, 256);
    int*    rowptr = (int*)p;   p += align_up((size_t)N * 4, 256);
    uint2*  seg    = (uint2*)p; p += align_up((size_t)NBUCK * SCAP * 8, 256); // 16.8 MB
    int*    col    = (int*)p;   p += align_up((size_t)NBUCK * SCAP * 4, 256); // 8.4 MB packed
    float*  W23    = (float*)p; p += align_up((size_t)128 * 64 * 4, 256);
    float*  Wc     = (float*)p; p += align_up((size_t)128 * 64 * 4, 256);
    ushort* Y      = (ushort*)p; p += align_up((size_t)N * 64 * 2, 256); // bf16 node table
    ushort* Za     = (ushort*)p; p += align_up((size_t)N * 64 * 2, 256); // bf16 ping-pong

    hipMemsetAsync(gcur, 0, (size_t)NREP * NBUCK * 4, stream);

    // ---- Pass A: bin edges; last block computes Wc = W1 @ (W2 @ W3) ----
    bin_wc<<<NBIN + 1, 256, 0, stream>>>(src, dst, gcur, seg, E,
                                         W1, W2, W3, W23, Wc);

    // ---- Pass B (blocks 0..255) overlapped with Y = X @ Wc (blocks 256..) ----
    const int gemm_blocks = (N + 127) / 128;             // 782
    csr_gemm<<<NBUCK + gemm_blocks, 256, 0, stream>>>(gcur, seg, col, cnt,
                                                      rowptr, x, Wc, Y, N);

    // ---- out = A^3 Y ----
    const int agg_blocks = (N * 8 + 255) / 256;          // 3125
    agg64<false><<<agg_blocks, 256, 0, stream>>>((const uint4*)Y,  cnt, col,
                                                 rowptr, Za, N);
    agg64<false><<<agg_blocks, 256, 0, stream>>>((const uint4*)Za, cnt, col,
                                                 rowptr, Y,  N);
    agg64<true ><<<agg_blocks, 256, 0, stream>>>((const uint4*)Y,  cnt, col,
                                                 rowptr, out, N);
}

// Round 12
// 241.755 us; speedup vs baseline: 1.0580x; 1.0046x over previous
//
#include <hip/hip_runtime.h>

#define N_NODES 100000
#define N_EDGES 1600000
#define CAP 48      // deg~Poisson(16); P(deg>=48)*N ~ 3e-6 -> no drops
#define NBUCK 256   // dst-range buckets
#define NPB 391     // nodes per bucket = ceil(100000/256)
#define SCAP 8192   // bucket segment capacity (also packed-col bucket region)
#define NREP 4      // gcur replicas; quarter cap 2048 = mean 1562 + 12 sigma
#define SCAP4 (SCAP / NREP)
#define EPB 4096    // edges per bin block
#define NBIN ((N_EDGES + EPB - 1) / EPB)     // 391

typedef unsigned int uint;
typedef unsigned short ushort;
typedef unsigned char uchar;

__device__ __forceinline__ void fma4(float4& c, float s, const float4& w) {
    c.x += s * w.x; c.y += s * w.y; c.z += s * w.z; c.w += s * w.w;
}

__device__ __forceinline__ ushort bf16r(float f) {   // fp32 -> bf16 RNE
    union { float f; uint u; } v; v.f = f;
    return (ushort)((v.u + 0x7fffu + ((v.u >> 16) & 1u)) >> 16);
}

// ---------------- fp32 GEMM block: 128 rows x 64 cols, 8x4 thread tile --------
// r5/r7/r8: row-interleaved tile (rows rg+16*r); residual LDS conflicts were
// CSR lc atomics, not this GEMM — tile closed.
struct alignas(16) GemmSmem {
    float Xs[128][36];   // stride 36: 16B-aligned rows
    float Ws[32][64];
};

template <typename OutT>
__device__ __forceinline__ void gemm64_block(GemmSmem& sm, int bid,
                                             const float* __restrict__ X,
                                             const float* __restrict__ W,
                                             OutT* __restrict__ H, int n) {
    const int tid  = threadIdx.x;
    const int row0 = bid * 128;
    const int rg   = tid >> 4;          // 0..15: rows rg, rg+16, ..., rg+112
    const int cg   = tid & 15;          // col group: cg*4

    float4 acc0[8];
#pragma unroll
    for (int r = 0; r < 8; r++) acc0[r] = make_float4(0.f, 0.f, 0.f, 0.f);

    const int lr = tid >> 1;
    const int lh = tid & 1;
    int grow = row0 + lr; if (grow > n - 1) grow = n - 1;   // clamp tail reads
    const float* gx_base = X + (size_t)grow * 128 + lh * 16;

    for (int k0 = 0; k0 < 128; k0 += 32) {
        const float* gx = gx_base + k0;
#pragma unroll
        for (int i = 0; i < 4; i++)
            *(float4*)&sm.Xs[lr][lh * 16 + 4 * i] = *(const float4*)(gx + 4 * i);
        const float4* gw = (const float4*)(W + (size_t)k0 * 64);
        float4* sw = (float4*)&sm.Ws[0][0];
#pragma unroll
        for (int i = 0; i < 2; i++) sw[tid + 256 * i] = gw[tid + 256 * i];
        __syncthreads();

#pragma unroll
        for (int kk = 0; kk < 32; kk += 4) {
            float4 w00 = *(const float4*)&sm.Ws[kk + 0][cg * 4];
            float4 w01 = *(const float4*)&sm.Ws[kk + 1][cg * 4];
            float4 w02 = *(const float4*)&sm.Ws[kk + 2][cg * 4];
            float4 w03 = *(const float4*)&sm.Ws[kk + 3][cg * 4];
#pragma unroll
            for (int r = 0; r < 8; r++) {
                float4 a = *(const float4*)&sm.Xs[rg + 16 * r][kk];
                fma4(acc0[r], a.x, w00);
                fma4(acc0[r], a.y, w01);
                fma4(acc0[r], a.z, w02);
                fma4(acc0[r], a.w, w03);
            }
        }
        __syncthreads();
    }

#pragma unroll
    for (int r = 0; r < 8; r++) {
        int row = row0 + rg + 16 * r;
        if (row < n) {
            if constexpr (sizeof(OutT) == 2) {   // bf16 epilogue, node-major
                ushort4 o0 = make_ushort4(bf16r(acc0[r].x), bf16r(acc0[r].y),
                                          bf16r(acc0[r].z), bf16r(acc0[r].w));
                *(ushort4*)&H[(size_t)row * 64 + cg * 4] = o0;
            } else {
                *(float4*)&H[(size_t)row * 64 + cg * 4] = *(float4*)&acc0[r];
            }
        }
    }
}

// ---------------- Pass A + weight collapse ----------------
// r12 changes: (1) seg packed to ONE uint/edge: (src<<9)|(dst-node0) — src
// <2^17, local dst <2^9 = 26 bits. Halves bin's global writes and CSR's seg
// reads. (2) 17-barrier Hillis-Steele scan -> 2-barrier shfl wave-scan
// (identical exclusive-scan values -> bit-identical placement). (3) uchar
// eb[] carries the bucket id for the writeout (doesn't fit in the 32-bit
// packed word).
union BinWcSmem {
    struct {
        int ecnt[NBUCK];
        int base[NBUCK];
        int lofs[NBUCK];
        int wsum[4];
        uint  estage[EPB];   // 16 KB packed staging
        uchar eb[EPB];       // 4 KB bucket ids
    } b;                     // ~23.3 KB
    GemmSmem g;              // 26.6 KB
};

__global__ void __launch_bounds__(256) bin_wc(const int* __restrict__ src,
                                              const int* __restrict__ dst,
                                              int* __restrict__ gcur,
                                              uint* __restrict__ seg, int E,
                                              const float* __restrict__ W1,
                                              const float* __restrict__ W2,
                                              const float* __restrict__ W3,
                                              float* __restrict__ W23,
                                              float* __restrict__ Wc) {
    __shared__ BinWcSmem sh;
    if (blockIdx.x == gridDim.x - 1) {      // weight-collapse block
        gemm64_block<float>(sh.g, 0, W2, W3, W23, 128);
        __syncthreads();                     // W23 global writes visible in-block
        gemm64_block<float>(sh.g, 0, W1, W23, Wc, 128);
        return;
    }
    const int t = threadIdx.x;
    sh.b.ecnt[t] = 0;                        // t spans exactly NBUCK
    __syncthreads();
    const int e0 = blockIdx.x * EPB;
    const int rep = blockIdx.x & (NREP - 1); // replica counter set for this block
    uint preg[EPB / 256];                    // packed (src<<9)|dn
    uint qreg[EPB / 256];                    // (bucket<<12)|slot
    // phase 1: LDS histogram; returned value IS this edge's in-bucket slot
#pragma unroll
    for (int k = 0; k < EPB / 256; k++) {
        int i = e0 + k * 256 + t;
        if (i < E) {
            int d = dst[i];
            int b = d / NPB;
            preg[k] = ((uint)src[i] << 9) | (uint)(d - b * NPB);
            int slot = atomicAdd(&sh.b.ecnt[b], 1);
            qreg[k] = ((uint)b << 12) | (uint)slot;
        }
    }
    __syncthreads();
    // phase 2a: one reserving atomic per non-empty bucket on this replica word
    const int c = sh.b.ecnt[t];
    sh.b.base[t] = (c > 0) ? atomicAdd(&gcur[rep * NBUCK + t], c) : 0;
    // phase 2b: exclusive scan via wave shfl-scan + 4 partials (2 barriers)
    int v = c;
#pragma unroll
    for (int off = 1; off < 64; off <<= 1) {
        int u = __shfl_up(v, off, 64);
        if ((t & 63) >= off) v += u;
    }
    if ((t & 63) == 63) sh.b.wsum[t >> 6] = v;
    __syncthreads();
    int woff = 0;
#pragma unroll
    for (int w = 0; w < 4; w++) if (w < (t >> 6)) woff += sh.b.wsum[w];
    const int excl = woff + v - c;
    sh.b.lofs[t] = excl;
    __syncthreads();
    // phase 3a: stage edges bucket-sorted in LDS (+ bucket id side-array)
#pragma unroll
    for (int k = 0; k < EPB / 256; k++) {
        int i = e0 + k * 256 + t;
        if (i < E) {
            int b = (int)(qreg[k] >> 12);
            int pos = sh.b.lofs[b] + (int)(qreg[k] & 4095u);
            sh.b.estage[pos] = preg[k];
            sh.b.eb[pos] = (uchar)b;
        }
    }
    __syncthreads();
    // phase 3b: coalesced write-out into this block's replica quarter
    const int total = min(E - e0, EPB);
    for (int i = t; i < total; i += 256) {
        uint w = sh.b.estage[i];
        int b = (int)sh.b.eb[i];
        int s = sh.b.base[b] + (i - sh.b.lofs[b]);
        if (s < SCAP4)
            seg[(size_t)b * SCAP + rep * SCAP4 + s] = w;
    }
}

// ---------------- Pass B + main GEMM (fused, heterogeneous blocks) ----------------
// r11 packed CSR (counting-sort per bucket, 4-aligned per-node offsets) kept;
// r12: seg is packed uints — unpack dn = w&511, src = w>>9.
union CsrGemmSmem {
    struct {
        int lc[NPB];
        int lrp[NPB];
        int sc[2][512];   // ping-pong scan buffer
    } c;                  // ~7.2 KB
    GemmSmem g;           // 26.6 KB
};

__global__ void __launch_bounds__(256, 3) csr_gemm(const int* __restrict__ gcur,
                                                   const uint* __restrict__ seg,
                                                   int* __restrict__ col,
                                                   int* __restrict__ cnt,
                                                   int* __restrict__ rowptr,
                                                   const float* __restrict__ X,
                                                   const float* __restrict__ Wc,
                                                   ushort* __restrict__ Y, int n) {
    __shared__ CsrGemmSmem sh;
    if (blockIdx.x < NBUCK) {
        const int b = blockIdx.x;
        const int t = threadIdx.x;
        const int node0 = b * NPB;
        for (int i = t; i < NPB; i += 256) sh.c.lc[i] = 0;
        __syncthreads();
        // pass A: per-node degree counts from the 4 seg quarters
#pragma unroll
        for (int q = 0; q < NREP; q++) {
            int m = gcur[q * NBUCK + b]; if (m > SCAP4) m = SCAP4;
            const uint* sg = seg + (size_t)b * SCAP + q * SCAP4;
            for (int i = t; i < m; i += 256)
                atomicAdd(&sh.c.lc[(int)(sg[i] & 511u)], 1);
        }
        __syncthreads();
        // scan of 4-rounded counts (Hillis-Steele over 512, 2 elems/thread)
        sh.c.sc[0][t]       = (t < NPB) ? ((sh.c.lc[t] + 3) & ~3) : 0;
        sh.c.sc[0][t + 256] = (t + 256 < NPB) ? ((sh.c.lc[t + 256] + 3) & ~3) : 0;
        __syncthreads();
        int pb = 0;
#pragma unroll
        for (int off = 1; off < 512; off <<= 1) {
            int a0 = sh.c.sc[pb][t];
            int a1 = sh.c.sc[pb][t + 256];
            int b0 = (t >= off) ? sh.c.sc[pb][t - off] : 0;
            int b1 = (t + 256 >= off) ? sh.c.sc[pb][t + 256 - off] : 0;
            sh.c.sc[pb ^ 1][t]       = a0 + b0;
            sh.c.sc[pb ^ 1][t + 256] = a1 + b1;
            __syncthreads();
            pb ^= 1;
        }
        // exclusive offsets (4-aligned); re-zero lc for placement pass
        if (t < NPB)
            sh.c.lrp[t] = sh.c.sc[pb][t] - ((sh.c.lc[t] + 3) & ~3);
        if (t + 256 < NPB)
            sh.c.lrp[t + 256] = sh.c.sc[pb][t + 256] - ((sh.c.lc[t + 256] + 3) & ~3);
        __syncthreads();
        for (int i = t; i < NPB; i += 256) sh.c.lc[i] = 0;
        __syncthreads();
        // pass B: place src packed
#pragma unroll
        for (int q = 0; q < NREP; q++) {
            int m = gcur[q * NBUCK + b]; if (m > SCAP4) m = SCAP4;
            const uint* sg = seg + (size_t)b * SCAP + q * SCAP4;
            for (int i = t; i < m; i += 256) {
                uint w = sg[i];
                int dn = (int)(w & 511u);
                int slot = atomicAdd(&sh.c.lc[dn], 1);
                int pos = sh.c.lrp[dn] + slot;
                if (pos < SCAP) col[(size_t)b * SCAP + pos] = (int)(w >> 9);
            }
        }
        __syncthreads();
        // publish cnt (capped) + absolute rowptr, coalesced
        for (int i = t; i < NPB; i += 256) {
            int node = node0 + i;
            if (node < n) {
                int c = sh.c.lc[i];
                cnt[node] = (c > CAP) ? CAP : c;
                rowptr[node] = b * SCAP + sh.c.lrp[i];
            }
        }
    } else {
        gemm64_block<ushort>(sh.g, blockIdx.x - NBUCK, X, Wc, Y, n);
    }
}

// ---------------- Aggregation, width 64, bf16 table [N][64] ----------------
// 8 lanes per node; lane owns a uint4 (8 dims) -> one coalesced 128 B
// (exactly one cacheline) gather per edge. r2: no dim-split. r11: packed
// col via rowptr (16 B-aligned by construction). At the random-gather
// MALL service floor (~5.9 TB/s effective) — the structural cost term.
__device__ __forceinline__ float2 bf2f(uint u) {
    union { uint u; float f; } a, b;
    a.u = u << 16; b.u = u & 0xffff0000u;
    return make_float2(a.f, b.f);
}

template <bool FINAL>
__global__ void __launch_bounds__(256) agg64(const uint4* __restrict__ T_in,
                                             const int* __restrict__ cnt,
                                             const int* __restrict__ col,
                                             const int* __restrict__ rowptr,
                                             void* __restrict__ T_out, int n) {
    int gid  = blockIdx.x * blockDim.x + threadIdx.x;
    int node = gid >> 3;
    int lane = gid & 7;                  // owns dims [8*lane, 8*lane+8)
    if (node >= n) return;
    int m = cnt[node]; if (m > CAP) m = CAP;
    const int* cb = col + rowptr[node];
    const uint4* tb = T_in + lane;
    float4 accA = make_float4(0.f, 0.f, 0.f, 0.f);
    float4 accB = make_float4(0.f, 0.f, 0.f, 0.f);
    int j = 0;
    for (; j + 8 <= m; j += 8) {
        int4 c0 = *(const int4*)&cb[j];
        int4 c1 = *(const int4*)&cb[j + 4];
        uint4 u0 = tb[(size_t)c0.x * 8];
        uint4 u1 = tb[(size_t)c0.y * 8];
        uint4 u2 = tb[(size_t)c0.z * 8];
        uint4 u3 = tb[(size_t)c0.w * 8];
        uint4 u4 = tb[(size_t)c1.x * 8];
        uint4 u5 = tb[(size_t)c1.y * 8];
        uint4 u6 = tb[(size_t)c1.z * 8];
        uint4 u7 = tb[(size_t)c1.w * 8];
        float2 p0 = bf2f(u0.x), p1 = bf2f(u1.x), p2 = bf2f(u2.x), p3 = bf2f(u3.x);
        float2 p4 = bf2f(u4.x), p5 = bf2f(u5.x), p6 = bf2f(u6.x), p7 = bf2f(u7.x);
        accA.x += ((p0.x + p1.x) + (p2.x + p3.x)) + ((p4.x + p5.x) + (p6.x + p7.x));
        accA.y += ((p0.y + p1.y) + (p2.y + p3.y)) + ((p4.y + p5.y) + (p6.y + p7.y));
        float2 q0 = bf2f(u0.y), q1 = bf2f(u1.y), q2 = bf2f(u2.y), q3 = bf2f(u3.y);
        float2 q4 = bf2f(u4.y), q5 = bf2f(u5.y), q6 = bf2f(u6.y), q7 = bf2f(u7.y);
        accA.z += ((q0.x + q1.x) + (q2.x + q3.x)) + ((q4.x + q5.x) + (q6.x + q7.x));
        accA.w += ((q0.y + q1.y) + (q2.y + q3.y)) + ((q4.y + q5.y) + (q6.y + q7.y));
        float2 r0 = bf2f(u0.z), r1 = bf2f(u1.z), r2 = bf2f(u2.z), r3 = bf2f(u3.z);
        float2 r4 = bf2f(u4.z), r5 = bf2f(u5.z), r6 = bf2f(u6.z), r7 = bf2f(u7.z);
        accB.x += ((r0.x + r1.x) + (r2.x + r3.x)) + ((r4.x + r5.x) + (r6.x + r7.x));
        accB.y += ((r0.y + r1.y) + (r2.y + r3.y)) + ((r4.y + r5.y) + (r6.y + r7.y));
        float2 s0 = bf2f(u0.w), s1 = bf2f(u1.w), s2 = bf2f(u2.w), s3 = bf2f(u3.w);
        float2 s4 = bf2f(u4.w), s5 = bf2f(u5.w), s6 = bf2f(u6.w), s7 = bf2f(u7.w);
        accB.z += ((s0.x + s1.x) + (s2.x + s3.x)) + ((s4.x + s5.x) + (s6.x + s7.x));
        accB.w += ((s0.y + s1.y) + (s2.y + s3.y)) + ((s4.y + s5.y) + (s6.y + s7.y));
    }
    for (; j + 4 <= m; j += 4) {
        int4 c0 = *(const int4*)&cb[j];
        uint4 u0 = tb[(size_t)c0.x * 8];
        uint4 u1 = tb[(size_t)c0.y * 8];
        uint4 u2 = tb[(size_t)c0.z * 8];
        uint4 u3 = tb[(size_t)c0.w * 8];
        float2 p0 = bf2f(u0.x), p1 = bf2f(u1.x), p2 = bf2f(u2.x), p3 = bf2f(u3.x);
        accA.x += (p0.x + p1.x) + (p2.x + p3.x);
        accA.y += (p0.y + p1.y) + (p2.y + p3.y);
        float2 q0 = bf2f(u0.y), q1 = bf2f(u1.y), q2 = bf2f(u2.y), q3 = bf2f(u3.y);
        accA.z += (q0.x + q1.x) + (q2.x + q3.x);
        accA.w += (q0.y + q1.y) + (q2.y + q3.y);
        float2 r0 = bf2f(u0.z), r1 = bf2f(u1.z), r2 = bf2f(u2.z), r3 = bf2f(u3.z);
        accB.x += (r0.x + r1.x) + (r2.x + r3.x);
        accB.y += (r0.y + r1.y) + (r2.y + r3.y);
        float2 s0 = bf2f(u0.w), s1 = bf2f(u1.w), s2 = bf2f(u2.w), s3 = bf2f(u3.w);
        accB.z += (s0.x + s1.x) + (s2.x + s3.x);
        accB.w += (s0.y + s1.y) + (s2.y + s3.y);
    }
    for (; j < m; j++) {
        uint4 u = tb[(size_t)cb[j] * 8];
        float2 p = bf2f(u.x), q = bf2f(u.y), r = bf2f(u.z), s = bf2f(u.w);
        accA.x += p.x; accA.y += p.y; accA.z += q.x; accA.w += q.y;
        accB.x += r.x; accB.y += r.y; accB.z += s.x; accB.w += s.y;
    }
    if (FINAL) {
        ((float4*)T_out)[(size_t)node * 16 + lane * 2]     = accA;
        ((float4*)T_out)[(size_t)node * 16 + lane * 2 + 1] = accB;
    } else {
        uint4 o;
        o.x = (uint)bf16r(accA.x) | ((uint)bf16r(accA.y) << 16);
        o.y = (uint)bf16r(accA.z) | ((uint)bf16r(accA.w) << 16);
        o.z = (uint)bf16r(accB.x) | ((uint)bf16r(accB.y) << 16);
        o.w = (uint)bf16r(accB.z) | ((uint)bf16r(accB.w) << 16);
        ((uint4*)T_out)[(size_t)node * 8 + lane] = o;
    }
}

// ---------------- launch ----------------
// ALGEBRAIC COLLAPSE: out = A(A(A X W1)W2)W3 = A^3 . X . (W1 W2 W3)
// Pipeline: [bin(packed-uint seg, shfl scan)+wc][packed-CSR || GEMM][agg x3].

static inline size_t align_up(size_t x, size_t a) { return (x + a - 1) & ~(a - 1); }

extern "C" void kernel_launch(void* const* d_in, const int* in_sizes, int n_in,
                              void* d_out, int out_size, void* d_ws, size_t ws_size,
                              hipStream_t stream) {
    const float* x  = (const float*)d_in[0];
    const int*   ei = (const int*)d_in[1];   // [2, E]
    const float* W1 = (const float*)d_in[2];
    const float* W2 = (const float*)d_in[3];
    const float* W3 = (const float*)d_in[4];
    float* out = (float*)d_out;

    const int N = N_NODES;
    const int E = N_EDGES;
    const int* src = ei;
    const int* dst = ei + E;

    // workspace carve-up (~45 MB)
    char* p = (char*)d_ws;
    int*    gcur   = (int*)p;   p += align_up((size_t)NREP * NBUCK * 4, 256);
    int*    cnt    = (int*)p;   p += align_up((size_t)N * 4, 256);
    int*    rowptr = (int*)p;   p += align_up((size_t)N * 4, 256);
    uint*   seg    = (uint*)p;  p += align_up((size_t)NBUCK * SCAP * 4, 256); // 8.4 MB packed
    int*    col    = (int*)p;   p += align_up((size_t)NBUCK * SCAP * 4, 256); // 8.4 MB packed
    float*  W23    = (float*)p; p += align_up((size_t)128 * 64 * 4, 256);
    float*  Wc     = (float*)p; p += align_up((size_t)128 * 64 * 4, 256);
    ushort* Y      = (ushort*)p; p += align_up((size_t)N * 64 * 2, 256); // bf16 node table
    ushort* Za     = (ushort*)p; p += align_up((size_t)N * 64 * 2, 256); // bf16 ping-pong

    hipMemsetAsync(gcur, 0, (size_t)NREP * NBUCK * 4, stream);

    // ---- Pass A: bin edges; last block computes Wc = W1 @ (W2 @ W3) ----
    bin_wc<<<NBIN + 1, 256, 0, stream>>>(src, dst, gcur, seg, E,
                                         W1, W2, W3, W23, Wc);

    // ---- Pass B (blocks 0..255) overlapped with Y = X @ Wc (blocks 256..) ----
    const int gemm_blocks = (N + 127) / 128;             // 782
    csr_gemm<<<NBUCK + gemm_blocks, 256, 0, stream>>>(gcur, seg, col, cnt,
                                                      rowptr, x, Wc, Y, N);

    // ---- out = A^3 Y ----
    const int agg_blocks = (N * 8 + 255) / 256;          // 3125
    agg64<false><<<agg_blocks, 256, 0, stream>>>((const uint4*)Y,  cnt, col,
                                                 rowptr, Za, N);
    agg64<false><<<agg_blocks, 256, 0, stream>>>((const uint4*)Za, cnt, col,
                                                 rowptr, Y,  N);
    agg64<true ><<<agg_blocks, 256, 0, stream>>>((const uint4*)Y,  cnt, col,
                                                 rowptr, out, N);
}